// Round 4
// baseline (142.869 us; speedup 1.0000x reference)
//
#include <hip/hip_runtime.h>
#include <hip/hip_bf16.h>
#include <stdint.h>

typedef float  f32x4 __attribute__((ext_vector_type(4)));
typedef short  s16x8 __attribute__((ext_vector_type(8)));

#define NB    8
#define CIN   64
#define COUT  64
#define HH    128
#define WW    512
#define NTAP  17
#define PADW  152
#define XROW  816            // PADW + WW + PADW

// ---------------------------------------------------------------------------
// FAST PATH (MFMA)
// ---------------------------------------------------------------------------

// weights in A-fragment order: wf[(((t*2+p)*4+m)*64+l)*8+j] =
//   weff[t][ci = p*32 + 8*(l>>4)+j][co = 16m + (l&15)]  (bf16)
__global__ __launch_bounds__(256) void prep_wfrag(
        const float* __restrict__ W, const float* __restrict__ Bv,
        __hip_bfloat16* __restrict__ wf, float* __restrict__ bsum) {
    int idx = blockIdx.x * 256 + threadIdx.x;      // 69,632 total
    if (idx < NTAP * 2 * 4 * 64 * 8) {
        int j  = idx & 7;
        int l  = (idx >> 3) & 63;
        int m  = (idx >> 9) & 3;
        int pp = (idx >> 11) & 1;
        int t  = idx >> 12;
        int ci = pp * 32 + 8 * (l >> 4) + j;
        int co = 16 * m + (l & 15);
        float v;
        if (t == 0) {
            v = 0.f;
            #pragma unroll
            for (int i = 0; i < NB; ++i) v += W[((i * COUT + co) * CIN + ci) * 3 + 1];
        } else if (t <= 8) {
            v = W[(((t - 1) * COUT + co) * CIN + ci) * 3 + 0];
        } else {
            v = W[(((t - 9) * COUT + co) * CIN + ci) * 3 + 2];
        }
        wf[idx] = __float2bfloat16(v);
    }
    if (idx < COUT) {
        float s = 0.f;
        #pragma unroll
        for (int i = 0; i < NB; ++i) s += Bv[i * COUT + idx];
        bsum[idx] = s;
    }
}

__global__ __launch_bounds__(256, 2) void hdc_mfma(
        const float* __restrict__ x, const __hip_bfloat16* __restrict__ wf,
        const float* __restrict__ bsum, float* __restrict__ out) {
    __shared__ int4 xs4[XROW * 4];                 // 52,224 B (one padded row)
    char* rowbase = (char*)xs4;

    const int tid  = threadIdx.x;
    const int wv   = tid >> 6;                     // wave 0..3
    const int lane = tid & 63;
    const int l15  = lane & 15;
    const int lhi  = lane >> 4;
    const int bh   = blockIdx.x;
    const int b    = bh >> 7, h = bh & 127;
    const int wlo  = wv * 128;                     // wave's 128-w slice

    f32x4 acc[4][8];
    #pragma unroll
    for (int m = 0; m < 4; ++m) {
        f32x4 bi = *reinterpret_cast<const f32x4*>(bsum + 16 * m + 4 * lhi);
        #pragma unroll
        for (int n = 0; n < 8; ++n) acc[m][n] = bi;
    }

    // zero halos once: rows [0,152) and [664,816) — 608 16B chunks each side
    {
        const int4 z{0, 0, 0, 0};
        for (int f = tid; f < 608; f += 256) {
            xs4[f] = z;                            // left halo
            xs4[2656 + f] = z;                     // right halo (664*4)
        }
    }

    static constexpr int OFFS[NTAP] = {0, -48, -76, -96, -111, -124, -135, -144, -152,
                                          48,  76,  96,  111,  124,  135,  144,  152};

    for (int p = 0; p < 2; ++p) {
        __syncthreads();                           // halo done / prev phase reads done
        // fused stage: read x (fp32, coalesced), cvt->bf16, swizzled LDS write.
        // Produces LDS[row=PADW+w][slot = c ^ ((row>>1)&3)] = bf16x8 of
        // ci = p*32 + c*8 + (0..7) at width w  — identical to round-3 layout.
        {
            #pragma unroll
            for (int it = 0; it < 8; ++it) {
                const int f = it * 256 + tid;      // 0..2047
                const int c = f >> 9;              // chunk 0..3 (8-ci group)
                const int w = f & 511;
                const float* src = x +
                    (((size_t)(b * CIN + p * 32 + c * 8) * HH + h) * WW) + w;
                float v[8];
                #pragma unroll
                for (int j = 0; j < 8; ++j) v[j] = src[(size_t)j * (HH * WW)];
                union { __hip_bfloat16 hs[8]; int4 iv; } pk;
                #pragma unroll
                for (int j = 0; j < 8; ++j) pk.hs[j] = __float2bfloat16(v[j]);
                const int row  = PADW + w;
                const int slot = c ^ ((row >> 1) & 3);
                *reinterpret_cast<int4*>(rowbase + row * 64 + slot * 16) = pk.iv;
            }
        }
        __syncthreads();

        const char* wbase = (const char*)wf + p * 4096 + lane * 16;
        #pragma unroll
        for (int t = 0; t < NTAP; ++t) {
            s16x8 af[4];
            #pragma unroll
            for (int m = 0; m < 4; ++m)
                af[m] = *reinterpret_cast<const s16x8*>(wbase + t * 8192 + m * 1024);

            const int ldsrow = PADW + wlo + l15 + OFFS[t];
            const int slot   = lhi ^ ((ldsrow >> 1) & 3);   // n-invariant (16n -> +8 in >>1)
            const char* bbase = rowbase + ldsrow * 64 + slot * 16;
            s16x8 bfr[8];
            #pragma unroll
            for (int n = 0; n < 8; ++n)
                bfr[n] = *reinterpret_cast<const s16x8*>(bbase + n * 1024);

            #pragma unroll
            for (int m = 0; m < 4; ++m)
                #pragma unroll
                for (int n = 0; n < 8; ++n)
                    acc[m][n] = __builtin_amdgcn_mfma_f32_16x16x32_bf16(
                        af[m], bfr[n], acc[m][n], 0, 0, 0);
        }
    }

    // epilogue: ReLU + store. D layout: col=l15 (w), row=4*lhi+r (co)
    float* obase = out + (((size_t)b * COUT + 4 * lhi) * HH + h) * WW + wlo + l15;
    #pragma unroll
    for (int m = 0; m < 4; ++m)
        #pragma unroll
        for (int n = 0; n < 8; ++n)
            #pragma unroll
            for (int r = 0; r < 4; ++r) {
                float v = acc[m][n][r];
                obase[(size_t)(16 * m + r) * (HH * WW) + 16 * n] = v > 0.f ? v : 0.f;
            }
}

// ---------------------------------------------------------------------------
// FALLBACK (round-1 fp32 kernel) if ws_size is too small for weights scratch
// ---------------------------------------------------------------------------
#define CI_STAGE 16

__global__ void prep_weff_fb(const float* __restrict__ W, const float* __restrict__ Bv,
                             float* __restrict__ weff, float* __restrict__ bsum) {
    int idx = blockIdx.x * 256 + threadIdx.x;
    if (idx < CIN * NTAP * COUT) {
        int co = idx & 63;
        int t  = (idx >> 6) % NTAP;
        int ci = idx / (NTAP * COUT);
        float v;
        if (t == 0) {
            v = 0.f;
            #pragma unroll
            for (int i = 0; i < NB; ++i) v += W[(((i * COUT + co) * CIN + ci) * 3) + 1];
        } else if (t <= 8) {
            v = W[((((t - 1) * COUT + co) * CIN + ci) * 3) + 0];
        } else {
            v = W[((((t - 9) * COUT + co) * CIN + ci) * 3) + 2];
        }
        weff[(ci * NTAP + t) * COUT + co] = v;
    }
    if (idx < COUT) {
        float s = 0.f;
        #pragma unroll
        for (int i = 0; i < NB; ++i) s += Bv[i * COUT + idx];
        bsum[idx] = s;
    }
}

__global__ __launch_bounds__(256, 2) void hdc_fb(
        const float* __restrict__ x, const float* __restrict__ weff,
        const float* __restrict__ bsum, float* __restrict__ out) {
    __shared__ float xsf[CI_STAGE][XROW];
    const int bh  = blockIdx.x;
    const int b   = bh >> 7;
    const int h   = bh & (HH - 1);
    const int tid = threadIdx.x;
    const int cg  = tid >> 5;
    const int wl  = tid & 31;
    constexpr int OFFS[NTAP] = {0, -48, -76, -96, -111, -124, -135, -144, -152,
                                    48,  76,  96,  111,  124,  135,  144,  152};
    float acc[8][16];
    #pragma unroll
    for (int j = 0; j < 8; ++j) {
        const float bj = bsum[cg * 8 + j];
        #pragma unroll
        for (int i = 0; i < 16; ++i) acc[j][i] = bj;
    }
    const float* xrowbase = x + ((size_t)(b * CIN) * HH + h) * WW;
    for (int s = 0; s < CIN / CI_STAGE; ++s) {
        __syncthreads();
        for (int f = tid; f < CI_STAGE * PADW; f += 256) {
            int r = f / PADW, c = f - r * PADW;
            xsf[r][c] = 0.f;
            xsf[r][PADW + WW + c] = 0.f;
        }
        #pragma unroll
        for (int j = 0; j < 8; ++j) {
            int flat = j * 256 + tid;
            int r = flat >> 7, c4 = flat & 127;
            const float4 v = *reinterpret_cast<const float4*>(
                xrowbase + (size_t)(s * CI_STAGE + r) * (HH * WW) + c4 * 4);
            *reinterpret_cast<float4*>(&xsf[r][PADW + c4 * 4]) = v;
        }
        __syncthreads();
        for (int r = 0; r < CI_STAGE; ++r) {
            const int ci = s * CI_STAGE + r;
            const float* wrow = weff + (size_t)(ci * NTAP) * COUT + cg * 8;
            const float* xr   = &xsf[r][PADW + wl];
            #pragma unroll
            for (int t = 0; t < NTAP; ++t) {
                const float4 w0 = *reinterpret_cast<const float4*>(wrow + t * COUT);
                const float4 w1 = *reinterpret_cast<const float4*>(wrow + t * COUT + 4);
                float xv[16];
                #pragma unroll
                for (int i = 0; i < 16; ++i) xv[i] = xr[OFFS[t] + 32 * i];
                const float wv[8] = {w0.x, w0.y, w0.z, w0.w, w1.x, w1.y, w1.z, w1.w};
                #pragma unroll
                for (int j = 0; j < 8; ++j)
                    #pragma unroll
                    for (int i = 0; i < 16; ++i)
                        acc[j][i] = fmaf(wv[j], xv[i], acc[j][i]);
            }
        }
    }
    float* outbase = out + (((size_t)b * COUT + cg * 8) * HH + h) * WW + wl;
    #pragma unroll
    for (int j = 0; j < 8; ++j)
        #pragma unroll
        for (int i = 0; i < 16; ++i) {
            float v = acc[j][i];
            outbase[(size_t)j * (HH * WW) + 32 * i] = v > 0.f ? v : 0.f;
        }
}

// ---------------------------------------------------------------------------

extern "C" void kernel_launch(void* const* d_in, const int* in_sizes, int n_in,
                              void* d_out, int out_size, void* d_ws, size_t ws_size,
                              hipStream_t stream) {
    const float* x  = (const float*)d_in[0];
    const float* W  = (const float*)d_in[1];
    const float* Bv = (const float*)d_in[2];
    float* out = (float*)d_out;

    const size_t need = 139264 + 256;              // wf + bsum

    if (ws_size >= need) {
        __hip_bfloat16* wf = (__hip_bfloat16*)d_ws;               // 139,264 B
        float* bsum = (float*)((char*)d_ws + 139264);             // 256 B
        prep_wfrag<<<272, 256, 0, stream>>>(W, Bv, wf, bsum);
        hdc_mfma<<<1024, 256, 0, stream>>>(x, wf, bsum, out);
    } else {
        float* weff = (float*)d_ws;
        float* bsum = weff + (size_t)CIN * NTAP * COUT;
        prep_weff_fb<<<(CIN * NTAP * COUT + 255) / 256, 256, 0, stream>>>(W, Bv, weff, bsum);
        hdc_fb<<<NB * HH, 256, 0, stream>>>(x, weff, bsum, out);
    }
}

// Round 5
// 124.080 us; speedup vs baseline: 1.1514x; 1.1514x over previous
//
#include <hip/hip_runtime.h>
#include <hip/hip_bf16.h>
#include <stdint.h>

typedef float  f32x4 __attribute__((ext_vector_type(4)));
typedef short  s16x8 __attribute__((ext_vector_type(8)));

#define NB    8
#define CIN   64
#define COUT  64
#define HH    128
#define WW    512
#define NTAP  17
#define PADW  152
#define XROW  816            // PADW + WW + PADW

// ---------------------------------------------------------------------------
// FAST PATH (MFMA)
// ---------------------------------------------------------------------------

// weights in A-fragment order: wf[(((t*2+p)*4+m)*64+l)*8+j] =
//   weff[t][ci = p*32 + 8*(l>>4)+j][co = 16m + (l&15)]  (bf16)
__global__ __launch_bounds__(256) void prep_wfrag(
        const float* __restrict__ W, const float* __restrict__ Bv,
        __hip_bfloat16* __restrict__ wf, float* __restrict__ bsum) {
    int idx = blockIdx.x * 256 + threadIdx.x;      // 69,632 total
    if (idx < NTAP * 2 * 4 * 64 * 8) {
        int j  = idx & 7;
        int l  = (idx >> 3) & 63;
        int m  = (idx >> 9) & 3;
        int pp = (idx >> 11) & 1;
        int t  = idx >> 12;
        int ci = pp * 32 + 8 * (l >> 4) + j;
        int co = 16 * m + (l & 15);
        float v;
        if (t == 0) {
            v = 0.f;
            #pragma unroll
            for (int i = 0; i < NB; ++i) v += W[((i * COUT + co) * CIN + ci) * 3 + 1];
        } else if (t <= 8) {
            v = W[(((t - 1) * COUT + co) * CIN + ci) * 3 + 0];
        } else {
            v = W[(((t - 9) * COUT + co) * CIN + ci) * 3 + 2];
        }
        wf[idx] = __float2bfloat16(v);
    }
    if (idx < COUT) {
        float s = 0.f;
        #pragma unroll
        for (int i = 0; i < NB; ++i) s += Bv[i * COUT + idx];
        bsum[idx] = s;
    }
}

// x -> bf16, PRE-SWIZZLED layout xt[b][h][p][w][slot]:
//   slot sc holds data chunk c = sc ^ ((w>>1)&3)   (involution)
// so that main's LINEAR global_load_lds produces LDS[row=PADW+w][slot] with
// chunk = slot ^ ((row>>1)&3)  — exactly what the swizzled ds_read expects
// (PADW=152 ≡ 0 mod 8 makes (row>>1)&3 == (w>>1)&3).
__global__ __launch_bounds__(256) void prep_xt(
        const float* __restrict__ x, __hip_bfloat16* __restrict__ xt) {
    __shared__ float tile[64][68];                 // [ci][w] padded (+4)
    int blk = blockIdx.x;                          // b*1024 + h*8 + wc
    int wc = blk & 7, h = (blk >> 3) & 127, b = blk >> 10;
    int w0 = wc * 64;
    int t = threadIdx.x;
    {
        int ci = t >> 2, q = t & 3;
        const float* src = x + (((size_t)b * CIN + ci) * HH + h) * WW + w0 + q * 16;
        float* dst = &tile[ci][q * 16];
        #pragma unroll
        for (int k = 0; k < 4; ++k)
            reinterpret_cast<float4*>(dst)[k] = reinterpret_cast<const float4*>(src)[k];
    }
    __syncthreads();
    int w = t & 63, sc = t >> 6;                   // sc = output slot 0..3
    int wg = w0 + w;
    int c = sc ^ ((wg >> 1) & 3);                  // data chunk stored at slot sc
    #pragma unroll
    for (int p = 0; p < 2; ++p) {
        int cibase = p * 32 + c * 8;
        union { __hip_bfloat16 hs[8]; int4 v; } pk;
        #pragma unroll
        for (int j = 0; j < 8; ++j) pk.hs[j] = __float2bfloat16(tile[cibase + j][w]);
        *reinterpret_cast<int4*>((char*)xt +
            ((((size_t)(b * HH + h) * 2 + p) * WW + wg) * 64 + sc * 16)) = pk.v;
    }
}

__global__ __launch_bounds__(256, 2) void hdc_mfma(
        const __hip_bfloat16* __restrict__ xt, const __hip_bfloat16* __restrict__ wf,
        const float* __restrict__ bsum, float* __restrict__ out) {
    __shared__ int4 xs4[XROW * 4];                 // 52,224 B (one padded row)
    char* rowbase = (char*)xs4;

    const int tid  = threadIdx.x;
    const int wv   = tid >> 6;                     // wave 0..3
    const int lane = tid & 63;
    const int l15  = lane & 15;
    const int lhi  = lane >> 4;
    const int bh   = blockIdx.x;
    const int b    = bh >> 7, h = bh & 127;
    const int wlo  = wv * 128;                     // wave's 128-w slice
    const char* xrow = (const char*)xt + (size_t)bh * 65536;

    f32x4 acc[4][8];
    #pragma unroll
    for (int m = 0; m < 4; ++m) {
        f32x4 bi = *reinterpret_cast<const f32x4*>(bsum + 16 * m + 4 * lhi);
        #pragma unroll
        for (int n = 0; n < 8; ++n) acc[m][n] = bi;
    }

    // zero halos once: rows [0,152) and [664,816) — 608 16B chunks each side
    {
        const int4 z{0, 0, 0, 0};
        for (int f = tid; f < 608; f += 256) {
            xs4[f] = z;                            // left halo
            xs4[2656 + f] = z;                     // right halo (664*4)
        }
    }

    static constexpr int OFFS[NTAP] = {0, -48, -76, -96, -111, -124, -135, -144, -152,
                                          48,  76,  96,  111,  124,  135,  144,  152};

    for (int p = 0; p < 2; ++p) {
        __syncthreads();                           // halo done / prev phase reads done
        // stage body: linear DMA global->LDS (source is pre-swizzled in xt)
        {
            const char* gsrc = xrow + p * 32768;
            #pragma unroll
            for (int it = 0; it < 8; ++it) {
                __builtin_amdgcn_global_load_lds(
                    (const __attribute__((address_space(1))) uint32_t*)
                        (gsrc + (it * 256 + tid) * 16),
                    (__attribute__((address_space(3))) uint32_t*)
                        (rowbase + PADW * 64 + (it * 256 + wv * 64) * 16),
                    16, 0, 0);
            }
        }
        __syncthreads();                           // drains vmcnt before barrier

        const char* wbase = (const char*)wf + p * 4096 + lane * 16;
        #pragma unroll
        for (int t = 0; t < NTAP; ++t) {
            s16x8 af[4];
            #pragma unroll
            for (int m = 0; m < 4; ++m)
                af[m] = *reinterpret_cast<const s16x8*>(wbase + t * 8192 + m * 1024);

            const int ldsrow = PADW + wlo + l15 + OFFS[t];
            const int slot   = lhi ^ ((ldsrow >> 1) & 3);   // n-invariant (16n -> +8 in >>1)
            const char* bbase = rowbase + ldsrow * 64 + slot * 16;
            s16x8 bfr[8];
            #pragma unroll
            for (int n = 0; n < 8; ++n)
                bfr[n] = *reinterpret_cast<const s16x8*>(bbase + n * 1024);

            #pragma unroll
            for (int m = 0; m < 4; ++m)
                #pragma unroll
                for (int n = 0; n < 8; ++n)
                    acc[m][n] = __builtin_amdgcn_mfma_f32_16x16x32_bf16(
                        af[m], bfr[n], acc[m][n], 0, 0, 0);
        }
    }

    // epilogue: ReLU + store. D layout: col=l15 (w), row=4*lhi+r (co)
    float* obase = out + (((size_t)b * COUT + 4 * lhi) * HH + h) * WW + wlo + l15;
    #pragma unroll
    for (int m = 0; m < 4; ++m)
        #pragma unroll
        for (int n = 0; n < 8; ++n)
            #pragma unroll
            for (int r = 0; r < 4; ++r) {
                float v = acc[m][n][r];
                obase[(size_t)(16 * m + r) * (HH * WW) + 16 * n] = v > 0.f ? v : 0.f;
            }
}

// ---------------------------------------------------------------------------
// FALLBACK (round-1 fp32 kernel) if ws_size is too small for the bf16 copy
// ---------------------------------------------------------------------------
#define CI_STAGE 16

__global__ void prep_weff_fb(const float* __restrict__ W, const float* __restrict__ Bv,
                             float* __restrict__ weff, float* __restrict__ bsum) {
    int idx = blockIdx.x * 256 + threadIdx.x;
    if (idx < CIN * NTAP * COUT) {
        int co = idx & 63;
        int t  = (idx >> 6) % NTAP;
        int ci = idx / (NTAP * COUT);
        float v;
        if (t == 0) {
            v = 0.f;
            #pragma unroll
            for (int i = 0; i < NB; ++i) v += W[(((i * COUT + co) * CIN + ci) * 3) + 1];
        } else if (t <= 8) {
            v = W[((((t - 1) * COUT + co) * CIN + ci) * 3) + 0];
        } else {
            v = W[((((t - 9) * COUT + co) * CIN + ci) * 3) + 2];
        }
        weff[(ci * NTAP + t) * COUT + co] = v;
    }
    if (idx < COUT) {
        float s = 0.f;
        #pragma unroll
        for (int i = 0; i < NB; ++i) s += Bv[i * COUT + idx];
        bsum[idx] = s;
    }
}

__global__ __launch_bounds__(256, 2) void hdc_fb(
        const float* __restrict__ x, const float* __restrict__ weff,
        const float* __restrict__ bsum, float* __restrict__ out) {
    __shared__ float xsf[CI_STAGE][XROW];
    const int bh  = blockIdx.x;
    const int b   = bh >> 7;
    const int h   = bh & (HH - 1);
    const int tid = threadIdx.x;
    const int cg  = tid >> 5;
    const int wl  = tid & 31;
    constexpr int OFFS[NTAP] = {0, -48, -76, -96, -111, -124, -135, -144, -152,
                                    48,  76,  96,  111,  124,  135,  144,  152};
    float acc[8][16];
    #pragma unroll
    for (int j = 0; j < 8; ++j) {
        const float bj = bsum[cg * 8 + j];
        #pragma unroll
        for (int i = 0; i < 16; ++i) acc[j][i] = bj;
    }
    const float* xrowbase = x + ((size_t)(b * CIN) * HH + h) * WW;
    for (int s = 0; s < CIN / CI_STAGE; ++s) {
        __syncthreads();
        for (int f = tid; f < CI_STAGE * PADW; f += 256) {
            int r = f / PADW, c = f - r * PADW;
            xsf[r][c] = 0.f;
            xsf[r][PADW + WW + c] = 0.f;
        }
        #pragma unroll
        for (int j = 0; j < 8; ++j) {
            int flat = j * 256 + tid;
            int r = flat >> 7, c4 = flat & 127;
            const float4 v = *reinterpret_cast<const float4*>(
                xrowbase + (size_t)(s * CI_STAGE + r) * (HH * WW) + c4 * 4);
            *reinterpret_cast<float4*>(&xsf[r][PADW + c4 * 4]) = v;
        }
        __syncthreads();
        for (int r = 0; r < CI_STAGE; ++r) {
            const int ci = s * CI_STAGE + r;
            const float* wrow = weff + (size_t)(ci * NTAP) * COUT + cg * 8;
            const float* xr   = &xsf[r][PADW + wl];
            #pragma unroll
            for (int t = 0; t < NTAP; ++t) {
                const float4 w0 = *reinterpret_cast<const float4*>(wrow + t * COUT);
                const float4 w1 = *reinterpret_cast<const float4*>(wrow + t * COUT + 4);
                float xv[16];
                #pragma unroll
                for (int i = 0; i < 16; ++i) xv[i] = xr[OFFS[t] + 32 * i];
                const float wv[8] = {w0.x, w0.y, w0.z, w0.w, w1.x, w1.y, w1.z, w1.w};
                #pragma unroll
                for (int j = 0; j < 8; ++j)
                    #pragma unroll
                    for (int i = 0; i < 16; ++i)
                        acc[j][i] = fmaf(wv[j], xv[i], acc[j][i]);
            }
        }
    }
    float* outbase = out + (((size_t)b * COUT + cg * 8) * HH + h) * WW + wl;
    #pragma unroll
    for (int j = 0; j < 8; ++j)
        #pragma unroll
        for (int i = 0; i < 16; ++i) {
            float v = acc[j][i];
            outbase[(size_t)j * (HH * WW) + 32 * i] = v > 0.f ? v : 0.f;
        }
}

// ---------------------------------------------------------------------------

extern "C" void kernel_launch(void* const* d_in, const int* in_sizes, int n_in,
                              void* d_out, int out_size, void* d_ws, size_t ws_size,
                              hipStream_t stream) {
    const float* x  = (const float*)d_in[0];
    const float* W  = (const float*)d_in[1];
    const float* Bv = (const float*)d_in[2];
    float* out = (float*)d_out;

    const size_t XT_OFF = (size_t)1 << 20;
    const size_t need = XT_OFF + (size_t)8 * HH * 2 * WW * 64;   // 1MB + 67,108,864

    if (ws_size >= need) {
        __hip_bfloat16* wf = (__hip_bfloat16*)d_ws;               // 139,264 B
        float* bsum = (float*)((char*)d_ws + 139264);             // 256 B
        __hip_bfloat16* xt = (__hip_bfloat16*)((char*)d_ws + XT_OFF);
        prep_wfrag<<<272, 256, 0, stream>>>(W, Bv, wf, bsum);
        prep_xt<<<8192, 256, 0, stream>>>(x, xt);
        hdc_mfma<<<1024, 256, 0, stream>>>(xt, wf, bsum, out);
    } else {
        float* weff = (float*)d_ws;
        float* bsum = weff + (size_t)CIN * NTAP * COUT;
        prep_weff_fb<<<(CIN * NTAP * COUT + 255) / 256, 256, 0, stream>>>(W, Bv, weff, bsum);
        hdc_fb<<<NB * HH, 256, 0, stream>>>(x, weff, bsum, out);
    }
}